// Round 1
// baseline (14094.556 us; speedup 1.0000x reference)
//
#include <hip/hip_runtime.h>

#define T_LEN 256
#define B_DIM 128
#define I_DIM 256
#define H_DIM 1024

// ---------------------------------------------------------------------------
// Kernel 1: x_proj GEMM.  C[m][n] = sum_k A[m][k]*W[n][k] + bias[n]
//   A = input  [M=T*B=32768, K=256]  (row-major)
//   W = W_in   [N=1024, K=256]       (row-major, i.e. already K-contiguous)
//   C = d_out  [M, N]
// 64x64 tile, BK=32, 256 threads, 4x4 register blocking.
// ---------------------------------------------------------------------------
__global__ __launch_bounds__(256) void xproj_gemm(
    const float* __restrict__ A, const float* __restrict__ W,
    const float* __restrict__ bias, float* __restrict__ C) {
  __shared__ float As[64][33];   // +1 pad breaks power-of-2 bank stride
  __shared__ float Ws[64][33];

  const int tid = threadIdx.x;
  const int m0 = blockIdx.y * 64;
  const int n0 = blockIdx.x * 64;
  const int ty = tid >> 4;   // 0..15
  const int tx = tid & 15;   // 0..15

  const int r   = tid >> 3;         // 0..31 (load row)
  const int c4  = (tid & 7) << 2;   // 0..28 (load col, float4)

  float acc[4][4] = {};

  for (int kc = 0; kc < I_DIM; kc += 32) {
#pragma unroll
    for (int p = 0; p < 2; ++p) {
      const int rr = r + p * 32;
      const float4 a = *(const float4*)(A + (size_t)(m0 + rr) * I_DIM + kc + c4);
      As[rr][c4 + 0] = a.x; As[rr][c4 + 1] = a.y;
      As[rr][c4 + 2] = a.z; As[rr][c4 + 3] = a.w;
      const float4 w = *(const float4*)(W + (size_t)(n0 + rr) * I_DIM + kc + c4);
      Ws[rr][c4 + 0] = w.x; Ws[rr][c4 + 1] = w.y;
      Ws[rr][c4 + 2] = w.z; Ws[rr][c4 + 3] = w.w;
    }
    __syncthreads();
#pragma unroll
    for (int k = 0; k < 32; ++k) {
      float av[4], wv[4];
#pragma unroll
      for (int i = 0; i < 4; ++i) av[i] = As[ty * 4 + i][k];
#pragma unroll
      for (int j = 0; j < 4; ++j) wv[j] = Ws[tx * 4 + j][k];
#pragma unroll
      for (int i = 0; i < 4; ++i)
#pragma unroll
        for (int j = 0; j < 4; ++j)
          acc[i][j] = fmaf(av[i], wv[j], acc[i][j]);
    }
    __syncthreads();
  }

  const float4 bv = *(const float4*)(bias + n0 + tx * 4);
#pragma unroll
  for (int i = 0; i < 4; ++i) {
    float4 o;
    o.x = acc[i][0] + bv.x;
    o.y = acc[i][1] + bv.y;
    o.z = acc[i][2] + bv.z;
    o.w = acc[i][3] + bv.w;
    *(float4*)(C + (size_t)(m0 + ty * 4 + i) * H_DIM + n0 + tx * 4) = o;
  }
}

// ---------------------------------------------------------------------------
// Kernel 2: one recurrence step, in place on xio = d_out + t*B*H.
//   xio[b][j] = relu(0.9*hp[b][j] + 0.1*(sum_k W[j][k]*hp[b][k] + b_hh[j] + xio[b][j]))
//   hprev: [B,H] (previous states) or [H] broadcast (h0) when hprev_is_vec.
// Block tile: 64 j  x 16 b.  256 threads: jj = tid&63 (one j), bg = tid>>6
// owns 4 consecutive b.  Grid (H/64, B/16) = (16, 8) = 128 blocks.
// ---------------------------------------------------------------------------
__global__ __launch_bounds__(256) void rnn_step(
    const float* __restrict__ hprev, const int hprev_is_vec,
    const float* __restrict__ W, const float* __restrict__ b_hh,
    float* __restrict__ xio) {
  __shared__ float Wsh[64][65];   // 65: bank stride 1 -> 2-way max (free)
  __shared__ float hsh[16][64];   // compute reads are wave-uniform (broadcast)

  const int tid = threadIdx.x;
  const int j0 = blockIdx.x * 64;
  const int b0 = blockIdx.y * 16;
  const int jj = tid & 63;
  const int bg = tid >> 6;             // 0..3

  const int lr  = tid >> 4;            // 0..15
  const int lc4 = (tid & 15) << 2;     // 0..60

  float acc[4] = {0.f, 0.f, 0.f, 0.f};

  for (int kc = 0; kc < H_DIM; kc += 64) {
    // stage W tile [64 x 64]
#pragma unroll
    for (int p = 0; p < 4; ++p) {
      const int rr = lr + p * 16;
      const float4 w = *(const float4*)(W + (size_t)(j0 + rr) * H_DIM + kc + lc4);
      Wsh[rr][lc4 + 0] = w.x; Wsh[rr][lc4 + 1] = w.y;
      Wsh[rr][lc4 + 2] = w.z; Wsh[rr][lc4 + 3] = w.w;
    }
    // stage h tile [16 x 64]
    float4 h4;
    if (hprev_is_vec)
      h4 = *(const float4*)(hprev + kc + lc4);
    else
      h4 = *(const float4*)(hprev + (size_t)(b0 + lr) * H_DIM + kc + lc4);
    hsh[lr][lc4 + 0] = h4.x; hsh[lr][lc4 + 1] = h4.y;
    hsh[lr][lc4 + 2] = h4.z; hsh[lr][lc4 + 3] = h4.w;
    __syncthreads();

#pragma unroll
    for (int k = 0; k < 64; ++k) {
      const float w = Wsh[jj][k];
#pragma unroll
      for (int i = 0; i < 4; ++i)
        acc[i] = fmaf(w, hsh[bg * 4 + i][k], acc[i]);
    }
    __syncthreads();
  }

  const int j = j0 + jj;
  const float bj = b_hh[j];
#pragma unroll
  for (int i = 0; i < 4; ++i) {
    const int b = b0 + bg * 4 + i;
    const float hp = hprev_is_vec ? hprev[j] : hprev[(size_t)b * H_DIM + j];
    const size_t idx = (size_t)b * H_DIM + j;
    float v = 0.9f * hp + 0.1f * (acc[i] + bj + xio[idx]);
    xio[idx] = v > 0.f ? v : 0.f;
  }
}

// ---------------------------------------------------------------------------
extern "C" void kernel_launch(void* const* d_in, const int* in_sizes, int n_in,
                              void* d_out, int out_size, void* d_ws, size_t ws_size,
                              hipStream_t stream) {
  const float* input = (const float*)d_in[0];  // [T,B,I]
  const float* W_in  = (const float*)d_in[1];  // [H,I]
  const float* b_in  = (const float*)d_in[2];  // [H]
  const float* W_hh  = (const float*)d_in[3];  // [H,H]
  const float* b_hh  = (const float*)d_in[4];  // [H]
  const float* h0    = (const float*)d_in[5];  // [H]
  float* out = (float*)d_out;                  // [T,B,H]

  // Phase 1: x_proj for all timesteps, written directly into d_out.
  dim3 g1(H_DIM / 64, (T_LEN * B_DIM) / 64);   // (16, 512)
  xproj_gemm<<<g1, 256, 0, stream>>>(input, W_in, b_in, out);

  // Phase 2: sequential recurrence, in place. d_out[t-1] is h_{t-1}.
  dim3 g2(H_DIM / 64, B_DIM / 16);             // (16, 8)
  for (int t = 0; t < T_LEN; ++t) {
    const float* hprev = (t == 0) ? h0 : out + (size_t)(t - 1) * B_DIM * H_DIM;
    rnn_step<<<g2, 256, 0, stream>>>(hprev, t == 0 ? 1 : 0, W_hh, b_hh,
                                     out + (size_t)t * B_DIM * H_DIM);
  }
}

// Round 2
// 5345.167 us; speedup vs baseline: 2.6369x; 2.6369x over previous
//
#include <hip/hip_runtime.h>
#include <hip/hip_bf16.h>

#define T_LEN 256
#define B_DIM 128
#define I_DIM 256
#define H_DIM 1024

// ---------------------------------------------------------------------------
// Phase 1: x_proj GEMM (unchanged from round 0).
// C[m][n] = sum_k A[m][k]*W[n][k] + bias[n];  A=[32768,256], W=[1024,256]
// ---------------------------------------------------------------------------
__global__ __launch_bounds__(256) void xproj_gemm(
    const float* __restrict__ A, const float* __restrict__ W,
    const float* __restrict__ bias, float* __restrict__ C) {
  __shared__ float As[64][33];
  __shared__ float Ws[64][33];

  const int tid = threadIdx.x;
  const int m0 = blockIdx.y * 64;
  const int n0 = blockIdx.x * 64;
  const int ty = tid >> 4;
  const int tx = tid & 15;
  const int r   = tid >> 3;
  const int c4  = (tid & 7) << 2;

  float acc[4][4] = {};

  for (int kc = 0; kc < I_DIM; kc += 32) {
#pragma unroll
    for (int p = 0; p < 2; ++p) {
      const int rr = r + p * 32;
      const float4 a = *(const float4*)(A + (size_t)(m0 + rr) * I_DIM + kc + c4);
      As[rr][c4 + 0] = a.x; As[rr][c4 + 1] = a.y;
      As[rr][c4 + 2] = a.z; As[rr][c4 + 3] = a.w;
      const float4 w = *(const float4*)(W + (size_t)(n0 + rr) * I_DIM + kc + c4);
      Ws[rr][c4 + 0] = w.x; Ws[rr][c4 + 1] = w.y;
      Ws[rr][c4 + 2] = w.z; Ws[rr][c4 + 3] = w.w;
    }
    __syncthreads();
#pragma unroll
    for (int k = 0; k < 32; ++k) {
      float av[4], wv[4];
#pragma unroll
      for (int i = 0; i < 4; ++i) av[i] = As[ty * 4 + i][k];
#pragma unroll
      for (int j = 0; j < 4; ++j) wv[j] = Ws[tx * 4 + j][k];
#pragma unroll
      for (int i = 0; i < 4; ++i)
#pragma unroll
        for (int j = 0; j < 4; ++j)
          acc[i][j] = fmaf(av[i], wv[j], acc[i][j]);
    }
    __syncthreads();
  }

  const float4 bv = *(const float4*)(bias + n0 + tx * 4);
#pragma unroll
  for (int i = 0; i < 4; ++i) {
    float4 o;
    o.x = acc[i][0] + bv.x;
    o.y = acc[i][1] + bv.y;
    o.z = acc[i][2] + bv.z;
    o.w = acc[i][3] + bv.w;
    *(float4*)(C + (size_t)(m0 + ty * 4 + i) * H_DIM + n0 + tx * 4) = o;
  }
}

// ---------------------------------------------------------------------------
// hT workspace layout (bf16, ping-pong):
//   hT[buf][half][k4][b][ks]   buf in {0,1}, half in {0,1} (b 0-63 / 64-127),
//   k4 in [0,256), b in [0,64), ks in [0,4)   (k = 4*k4 + ks)
// One buffer = 2*256*64*4 = 131072 bf16 = 256 KB. Two buffers = 512 KB of ws.
// Packed-4k per b so one uint2 (8B) load yields 4 consecutive k values,
// coalesced 512 B per wave.
// ---------------------------------------------------------------------------
#define HT_BUF_ELEMS (2 * 256 * 64 * 4)   // 131072
#define HT_HALF_ELEMS (256 * 64 * 4)      // 65536

__global__ __launch_bounds__(256) void init_hT(
    const float* __restrict__ h0, __hip_bfloat16* __restrict__ hT) {
  const int idx = blockIdx.x * 256 + threadIdx.x;   // [0, 131072)
  const int ks = idx & 3;
  const int k4 = (idx >> 8) & 255;
  hT[idx] = __float2bfloat16(h0[k4 * 4 + ks]);
}

// ---------------------------------------------------------------------------
// Phase 2 step kernel v2.
// Grid: 256 blocks = 128 j-tiles (8 j each) x 2 b-halves. Block: 256 thr = 4
// waves; wave w owns j = jt*8 + 2w + {0,1}; lane = local b (0..63).
// W[j][k] is wave-uniform -> scalar loads (SGPR operand of v_fmac).
// h comes from the bf16 packed hT buffer, read directly from L2 (no LDS
// staging): per 4 k's one uint2 load + 2 unpack-pairs + 8 fmac.
// Epilogue transposes rec through 2 KB LDS, applies leak+relu in fp32 using
// exact fp32 h_prev from d_out[t-1], writes d_out[t] and hTnext.
// ---------------------------------------------------------------------------
__global__ __launch_bounds__(256) void rnn_step2(
    const __hip_bfloat16* __restrict__ hTprev,  // [2][256][64][4]
    __hip_bfloat16* __restrict__ hTnext,
    const float* __restrict__ W,                // [1024][1024]
    const float* __restrict__ b_hh,
    const float* __restrict__ hp_full,          // d_out[t-1] ([B,H]) or h0 ([H])
    const int hp_is_vec,
    float* __restrict__ xio)                    // d_out[t]: in = x_proj, out = h_t
{
  __shared__ float recS[8][72];   // 8 j-rows; 72 stride -> max 2-way bank alias (free)

  const int tid  = threadIdx.x;
  const int jt   = blockIdx.x >> 1;             // 0..127
  const int half = blockIdx.x & 1;
  const int wv   = __builtin_amdgcn_readfirstlane(tid >> 6);  // 0..3, force SGPR
  const int lane = tid & 63;                    // local b

  const int j0 = jt * 8 + wv * 2;               // wave-uniform
  const float* __restrict__ w0 = W + (size_t)j0 * H_DIM;
  const float* __restrict__ w1 = w0 + H_DIM;

  const uint2* __restrict__ hp8 =
      (const uint2*)(hTprev + (size_t)half * HT_HALF_ELEMS) + lane;

  float acc0 = 0.f, acc1 = 0.f;

  for (int k4 = 0; k4 < 256; k4 += 8) {
    uint2 hv[8];
#pragma unroll
    for (int u = 0; u < 8; ++u) hv[u] = hp8[(size_t)(k4 + u) * 64];
#pragma unroll
    for (int u = 0; u < 8; ++u) {
      const int k = (k4 + u) * 4;
      const float h0f = __uint_as_float(hv[u].x << 16);
      const float h1f = __uint_as_float(hv[u].x & 0xffff0000u);
      const float h2f = __uint_as_float(hv[u].y << 16);
      const float h3f = __uint_as_float(hv[u].y & 0xffff0000u);
      acc0 = fmaf(w0[k + 0], h0f, acc0);  acc1 = fmaf(w1[k + 0], h0f, acc1);
      acc0 = fmaf(w0[k + 1], h1f, acc0);  acc1 = fmaf(w1[k + 1], h1f, acc1);
      acc0 = fmaf(w0[k + 2], h2f, acc0);  acc1 = fmaf(w1[k + 2], h2f, acc1);
      acc0 = fmaf(w0[k + 3], h3f, acc0);  acc1 = fmaf(w1[k + 3], h3f, acc1);
    }
  }

  recS[wv * 2 + 0][lane] = acc0;
  recS[wv * 2 + 1][lane] = acc1;
  __syncthreads();

  // 512 outputs / 256 threads = 2 passes. lane-fast index = j (8-wide, 32 B
  // bursts; fine for L2-resident data).
  const int j  = tid & 7;
  const int jg = jt * 8 + j;
  const float bj = b_hh[jg];
#pragma unroll
  for (int p = 0; p < 2; ++p) {
    const int bl = (tid >> 3) + p * 32;         // local b
    const int bg = half * 64 + bl;              // global b
    const float rec = recS[j][bl];
    const size_t oidx = (size_t)bg * H_DIM + jg;
    const float xp = xio[oidx];                 // phase-1 x_proj value
    const float hp = hp_is_vec ? hp_full[jg] : hp_full[oidx];  // exact fp32 state
    float v = 0.9f * hp + 0.1f * (rec + bj + xp);
    v = v > 0.f ? v : 0.f;
    xio[oidx] = v;
    // hTnext[half][jg>>2][bl][jg&3]
    hTnext[(size_t)half * HT_HALF_ELEMS + (size_t)(jg >> 2) * 256 + bl * 4 + (jg & 3)] =
        __float2bfloat16(v);
  }
}

// ---------------------------------------------------------------------------
extern "C" void kernel_launch(void* const* d_in, const int* in_sizes, int n_in,
                              void* d_out, int out_size, void* d_ws, size_t ws_size,
                              hipStream_t stream) {
  const float* input = (const float*)d_in[0];
  const float* W_in  = (const float*)d_in[1];
  const float* b_in  = (const float*)d_in[2];
  const float* W_hh  = (const float*)d_in[3];
  const float* b_hh  = (const float*)d_in[4];
  const float* h0    = (const float*)d_in[5];
  float* out = (float*)d_out;

  __hip_bfloat16* hT = (__hip_bfloat16*)d_ws;   // 2 buffers of HT_BUF_ELEMS

  // Fill hT buffer 0 from h0 (ws is re-poisoned before every call).
  init_hT<<<HT_BUF_ELEMS / 256, 256, 0, stream>>>(h0, hT);

  // Phase 1: x_proj into d_out.
  dim3 g1(H_DIM / 64, (T_LEN * B_DIM) / 64);
  xproj_gemm<<<g1, 256, 0, stream>>>(input, W_in, b_in, out);

  // Phase 2: 256 sequential steps, ping-pong hT.
  for (int t = 0; t < T_LEN; ++t) {
    const __hip_bfloat16* hprev = hT + (size_t)(t & 1) * HT_BUF_ELEMS;
    __hip_bfloat16* hnext       = hT + (size_t)((t + 1) & 1) * HT_BUF_ELEMS;
    const float* hp_full = (t == 0) ? h0 : out + (size_t)(t - 1) * B_DIM * H_DIM;
    rnn_step2<<<256, 256, 0, stream>>>(hprev, hnext, W_hh, b_hh,
                                       hp_full, t == 0 ? 1 : 0,
                                       out + (size_t)t * B_DIM * H_DIM);
  }
}

// Round 3
// 2142.321 us; speedup vs baseline: 6.5791x; 2.4950x over previous
//
#include <hip/hip_runtime.h>
#include <hip/hip_bf16.h>

#define T_LEN 256
#define B_DIM 128
#define I_DIM 256
#define H_DIM 1024

typedef __attribute__((ext_vector_type(8))) short short8;
typedef __attribute__((ext_vector_type(4))) float f32x4;

// RNE float->bf16 (self-contained; inputs here are never NaN)
static __device__ __forceinline__ unsigned short f2bf(float f) {
  unsigned u = __float_as_uint(f);
  return (unsigned short)((u + 0x7fffu + ((u >> 16) & 1u)) >> 16);
}

// ---------------------------------------------------------------------------
// Phase 1: x_proj GEMM (fp32, unchanged).
// ---------------------------------------------------------------------------
__global__ __launch_bounds__(256) void xproj_gemm(
    const float* __restrict__ A, const float* __restrict__ W,
    const float* __restrict__ bias, float* __restrict__ C) {
  __shared__ float As[64][33];
  __shared__ float Ws[64][33];

  const int tid = threadIdx.x;
  const int m0 = blockIdx.y * 64;
  const int n0 = blockIdx.x * 64;
  const int ty = tid >> 4;
  const int tx = tid & 15;
  const int r   = tid >> 3;
  const int c4  = (tid & 7) << 2;

  float acc[4][4] = {};

  for (int kc = 0; kc < I_DIM; kc += 32) {
#pragma unroll
    for (int p = 0; p < 2; ++p) {
      const int rr = r + p * 32;
      const float4 a = *(const float4*)(A + (size_t)(m0 + rr) * I_DIM + kc + c4);
      As[rr][c4 + 0] = a.x; As[rr][c4 + 1] = a.y;
      As[rr][c4 + 2] = a.z; As[rr][c4 + 3] = a.w;
      const float4 w = *(const float4*)(W + (size_t)(n0 + rr) * I_DIM + kc + c4);
      Ws[rr][c4 + 0] = w.x; Ws[rr][c4 + 1] = w.y;
      Ws[rr][c4 + 2] = w.z; Ws[rr][c4 + 3] = w.w;
    }
    __syncthreads();
#pragma unroll
    for (int k = 0; k < 32; ++k) {
      float av[4], wv[4];
#pragma unroll
      for (int i = 0; i < 4; ++i) av[i] = As[ty * 4 + i][k];
#pragma unroll
      for (int j = 0; j < 4; ++j) wv[j] = Ws[tx * 4 + j][k];
#pragma unroll
      for (int i = 0; i < 4; ++i)
#pragma unroll
        for (int j = 0; j < 4; ++j)
          acc[i][j] = fmaf(av[i], wv[j], acc[i][j]);
    }
    __syncthreads();
  }

  const float4 bv = *(const float4*)(bias + n0 + tx * 4);
#pragma unroll
  for (int i = 0; i < 4; ++i) {
    float4 o;
    o.x = acc[i][0] + bv.x;
    o.y = acc[i][1] + bv.y;
    o.z = acc[i][2] + bv.z;
    o.w = acc[i][3] + bv.w;
    *(float4*)(C + (size_t)(m0 + ty * 4 + i) * H_DIM + n0 + tx * 4) = o;
  }
}

// ---------------------------------------------------------------------------
// One-time converts: W_hh -> bf16 [j][k]; hT0 -> bf16 [b][k] broadcast of h0.
// (ws is re-poisoned before every timed call, so these run every call.)
// ---------------------------------------------------------------------------
__global__ __launch_bounds__(256) void cvt_w_bf16(
    const float* __restrict__ W, unsigned short* __restrict__ Wb) {
  const int i4 = blockIdx.x * 256 + threadIdx.x;     // one float4 per thread
  const float4 w = ((const float4*)W)[i4];
  ushort4 o;
  o.x = f2bf(w.x); o.y = f2bf(w.y); o.z = f2bf(w.z); o.w = f2bf(w.w);
  ((ushort4*)Wb)[i4] = o;
}

__global__ __launch_bounds__(256) void init_hT0(
    const float* __restrict__ h0, unsigned short* __restrict__ hT) {
  const int idx = blockIdx.x * 256 + threadIdx.x;    // [0, 131072)
  hT[idx] = f2bf(h0[idx & (H_DIM - 1)]);
}

// ---------------------------------------------------------------------------
// Phase 2 step kernel v3: bf16 MFMA.
//   rec[b][j] = sum_k h[b][k] * W[j][k]   via mfma_f32_16x16x32_bf16
// Grid 256 = 64 j-tiles (16 j) x 4 b-quarters (32 b). Block 256 thr = 4 waves:
// wave w -> m-tile (w&1: which 16 of the 32 b) x k-half (w>>1: 512 k).
// A-frag: lane holds h[b0+(lane&15)][k + (lane>>4)*8 ..+7]  (16B contiguous)
// B-frag: lane holds W[j0+(lane&15)][k + (lane>>4)*8 ..+7]  (16B contiguous)
// k-half partials combined through LDS; epilogue (waves 0,1) in fp32 with
// exact fp32 h_prev from d_out[t-1] for the leak term.
// ---------------------------------------------------------------------------
__global__ __launch_bounds__(256) void rnn_step3(
    const unsigned short* __restrict__ hTprev,  // [128][1024] bf16
    unsigned short* __restrict__ hTnext,        // [128][1024] bf16
    const unsigned short* __restrict__ Wb,      // [1024][1024] bf16
    const float* __restrict__ b_hh,
    const float* __restrict__ hp_full,          // d_out[t-1] or h0
    const int hp_is_vec,
    float* __restrict__ xio)                    // d_out[t]: in x_proj, out h_t
{
  __shared__ float red[2][16][17];   // [m-tile][b_local][j_local], +1 pad

  const int tid  = threadIdx.x;
  const int wv   = tid >> 6;
  const int lane = tid & 63;
  const int ln   = lane & 15;        // A: b-row / B: j-row / D: j-col
  const int q    = lane >> 4;        // 0..3

  const int jt = blockIdx.x & 63;
  const int bq = blockIdx.x >> 6;
  const int j0 = jt * 16;
  const int mt = wv & 1;             // m-tile within the 32-b quarter
  const int kh = wv >> 1;            // k-half
  const int b0 = bq * 32 + mt * 16;

  const short8* __restrict__ ha =
      (const short8*)(hTprev + (size_t)(b0 + ln) * H_DIM + kh * 512 + q * 8);
  const short8* __restrict__ wb =
      (const short8*)(Wb + (size_t)(j0 + ln) * H_DIM + kh * 512 + q * 8);

  f32x4 acc = {0.f, 0.f, 0.f, 0.f};
#pragma unroll
  for (int kc = 0; kc < 16; ++kc) {   // 16 chunks of K=32; stride 32 elems = 4 short8
    const short8 a = ha[kc * 4];
    const short8 b = wb[kc * 4];
    acc = __builtin_amdgcn_mfma_f32_16x16x32_bf16(a, b, acc, 0, 0, 0);
  }

  // D layout: j_col = lane&15, b_row = (lane>>4)*4 + reg.
  if (wv >= 2) {
#pragma unroll
    for (int r = 0; r < 4; ++r) red[mt][q * 4 + r][ln] = acc[r];
  }
  __syncthreads();
  if (wv < 2) {
    const int jg = j0 + ln;
    const float bj = b_hh[jg];
#pragma unroll
    for (int r = 0; r < 4; ++r) {
      const float rec = acc[r] + red[mt][q * 4 + r][ln];
      const int bg = b0 + q * 4 + r;
      const size_t oidx = (size_t)bg * H_DIM + jg;
      const float xp = xio[oidx];
      const float hp = hp_is_vec ? hp_full[jg] : hp_full[oidx];
      float v = 0.9f * hp + 0.1f * (rec + bj + xp);
      v = v > 0.f ? v : 0.f;
      xio[oidx] = v;
      hTnext[oidx] = f2bf(v);
    }
  }
}

// ---------------------------------------------------------------------------
extern "C" void kernel_launch(void* const* d_in, const int* in_sizes, int n_in,
                              void* d_out, int out_size, void* d_ws, size_t ws_size,
                              hipStream_t stream) {
  const float* input = (const float*)d_in[0];
  const float* W_in  = (const float*)d_in[1];
  const float* b_in  = (const float*)d_in[2];
  const float* W_hh  = (const float*)d_in[3];
  const float* b_hh  = (const float*)d_in[4];
  const float* h0    = (const float*)d_in[5];
  float* out = (float*)d_out;

  // ws layout: [0, 2MB) Wb bf16 [1024][1024]; then hT ping-pong 2 x 256 KB.
  unsigned short* Wb = (unsigned short*)d_ws;
  unsigned short* hT = Wb + (1 << 20);
  const size_t HT_ELEMS = (size_t)B_DIM * H_DIM;   // 131072

  cvt_w_bf16<<<(H_DIM * H_DIM / 4) / 256, 256, 0, stream>>>(W_hh, Wb);
  init_hT0<<<(B_DIM * H_DIM) / 256, 256, 0, stream>>>(h0, hT);

  dim3 g1(H_DIM / 64, (T_LEN * B_DIM) / 64);
  xproj_gemm<<<g1, 256, 0, stream>>>(input, W_in, b_in, out);

  for (int t = 0; t < T_LEN; ++t) {
    const unsigned short* hprev = hT + (size_t)(t & 1) * HT_ELEMS;
    unsigned short* hnext       = hT + (size_t)((t + 1) & 1) * HT_ELEMS;
    const float* hp_full = (t == 0) ? h0 : out + (size_t)(t - 1) * B_DIM * H_DIM;
    rnn_step3<<<256, 256, 0, stream>>>(hprev, hnext, Wb, b_hh,
                                       hp_full, t == 0 ? 1 : 0,
                                       out + (size_t)t * B_DIM * H_DIM);
  }
}